// Round 8
// baseline (59.237 us; speedup 1.0000x reference)
//
#include <hip/hip_runtime.h>

// ---------------------------------------------------------------------------
// QuantumEntanglementLayer: 4 qubits, DIM=16, BATCH=2^20.
// out[b][w] = s^T A_w s,  A_w = Re(U^H Z_w U),  s = tensor prod of RY(|0>).
// Reduced to 4 multilinear polynomials with 81 coeffs each in (1,u_w,v_w).
//
// MEASUREMENT ROUND: identical to the 36.36us round-6 kernel, but qel_main
// is dispatched TWICE (idempotent). total = setup + 2*main + overhead, so
// main = total - 36.36. Three structurally different mains (4-sample,
// +schedbar, 8-sample) all measured 36.2-36.4us; the decomposition of that
// 36us among {setup, main, dispatch overhead} has never been observed
// directly (fills mask both kernels in the top-5 counter rows).
// ---------------------------------------------------------------------------

// Coefficients: [4 wires][27 (f0,f1,f2)][4 (f3 in .x/.y/.z, .w = pad)]
__device__ float g_coef[4 * 27 * 4];

__device__ __forceinline__ float hwsin(float rad) {
  return __builtin_amdgcn_sinf(rad * 0.15915494309189535f);  // rad -> rev
}
__device__ __forceinline__ float hwcos(float rad) {
  return __builtin_amdgcn_cosf(rad * 0.15915494309189535f);
}

__global__ __launch_bounds__(256) void qel_setup(const float* __restrict__ params) {
  __shared__ float2 U2[16][17];            // [col][row] (re,im), +1 pad
  __shared__ float A[4][16][16];           // A_w
  __shared__ float S1[4][3][8][8];         // after contracting qubit0 (f0)
  __shared__ float S2[4][3][3][4][4];      // + qubit1 (f1)
  __shared__ float S3[4][3][3][3][2][2];   // + qubit2 (f2)
  const int tid = threadIdx.x;

  // ---- Phase 1: 16 lanes, one U-column in registers, fully unrolled ------
  if (tid < 16) {
    const int c = tid;
    float ur[16], ui[16];
    #pragma unroll
    for (int r = 0; r < 16; r++) { ur[r] = (r == c) ? 1.f : 0.f; ui[r] = 0.f; }

    #pragma unroll
    for (int layer = 0; layer < 2; layer++) {
      #pragma unroll
      for (int r = 0; r < 16; r++) {       // CNOT(0,1): cm=8, tm=4
        if ((r & 8) && !(r & 4)) {
          float t;
          t = ur[r]; ur[r] = ur[r + 4]; ur[r + 4] = t;
          t = ui[r]; ui[r] = ui[r + 4]; ui[r + 4] = t;
        }
      }
      #pragma unroll
      for (int r = 0; r < 16; r++) {       // CNOT(1,2): cm=4, tm=2
        if ((r & 4) && !(r & 2)) {
          float t;
          t = ur[r]; ur[r] = ur[r + 2]; ur[r + 2] = t;
          t = ui[r]; ui[r] = ui[r + 2]; ui[r + 2] = t;
        }
      }
      #pragma unroll
      for (int r = 0; r < 16; r++) {       // CNOT(2,3): cm=2, tm=1
        if ((r & 2) && !(r & 1)) {
          float t;
          t = ur[r]; ur[r] = ur[r + 1]; ur[r + 1] = t;
          t = ui[r]; ui[r] = ui[r + 1]; ui[r + 1] = t;
        }
      }
      #pragma unroll
      for (int w = 0; w < 4; w++) {        // Rot(phi,theta,omega) on wire w
        float phi   = params[layer * 12 + w * 3 + 0];
        float theta = params[layer * 12 + w * 3 + 1];
        float omega = params[layer * 12 + w * 3 + 2];
        float ct = hwcos(theta * 0.5f), st = hwsin(theta * 0.5f);
        float ap = -0.5f * (phi + omega), am = 0.5f * (phi - omega);
        float g00r =  hwcos(ap) * ct, g00i =  hwsin(ap) * ct;
        float g01r = -hwcos(am) * st, g01i = -hwsin(am) * st;
        float g10r =  hwcos(am) * st, g10i = -hwsin(am) * st;
        float g11r =  g00r,           g11i = -g00i;
        const int tm = 8 >> w;
        #pragma unroll
        for (int r = 0; r < 16; r++) {
          if (r & tm) continue;
          const int r1 = r | tm;
          float s0r = ur[r],  s0i = ui[r];
          float s1r = ur[r1], s1i = ui[r1];
          ur[r]  = g00r*s0r - g00i*s0i + g01r*s1r - g01i*s1i;
          ui[r]  = g00r*s0i + g00i*s0r + g01r*s1i + g01i*s1r;
          ur[r1] = g10r*s0r - g10i*s0i + g11r*s1r - g11i*s1i;
          ui[r1] = g10r*s0i + g10i*s0r + g11r*s1i + g11i*s1r;
        }
      }
      #pragma unroll
      for (int r = 0; r < 16; r++) {       // CNOT(0,3): cm=8, tm=1
        if ((r & 8) && !(r & 1)) {
          float t;
          t = ur[r]; ur[r] = ur[r + 1]; ur[r + 1] = t;
          t = ui[r]; ui[r] = ui[r + 1]; ui[r + 1] = t;
        }
      }
    }
    #pragma unroll
    for (int r = 0; r < 16; r++) U2[c][r] = make_float2(ur[r], ui[r]);
  }
  __syncthreads();

  // ---- Phase 2: A_w[j][k] = sum_i z_w[i] (Re_i_j Re_i_k + Im_i_j Im_i_k) -
  {
    const int j = tid >> 4, k = tid & 15;
    float s0 = 0.f, s1 = 0.f, s2 = 0.f, s3 = 0.f;
    #pragma unroll
    for (int i = 0; i < 16; i++) {
      float2 uj = U2[j][i], uk = U2[k][i];
      float p = uj.x * uk.x + uj.y * uk.y;
      s0 += (i & 8) ? -p : p;
      s1 += (i & 4) ? -p : p;
      s2 += (i & 2) ? -p : p;
      s3 += (i & 1) ? -p : p;
    }
    A[0][j][k] = s0; A[1][j][k] = s1; A[2][j][k] = s2; A[3][j][k] = s3;
  }
  __syncthreads();

  // Basis per 2x2 block: f=0: .5(x00+x11)  f=1: .5(x00-x11)  f=2: .5(x01+x10)
  {  // Phase 3a: contract qubit0 (bit3)
    const int w = tid >> 6, j = (tid >> 3) & 7, k = tid & 7;
    float x00 = A[w][j][k],     x01 = A[w][j][k + 8];
    float x10 = A[w][j + 8][k], x11 = A[w][j + 8][k + 8];
    S1[w][0][j][k] = 0.5f * (x00 + x11);
    S1[w][1][j][k] = 0.5f * (x00 - x11);
    S1[w][2][j][k] = 0.5f * (x01 + x10);
  }
  __syncthreads();
  if (tid < 192) {  // Phase 3b: + qubit1
    const int w = tid / 48, r = tid % 48;
    const int f0 = r >> 4, j = (r >> 2) & 3, k = r & 3;
    float x00 = S1[w][f0][j][k],     x01 = S1[w][f0][j][k + 4];
    float x10 = S1[w][f0][j + 4][k], x11 = S1[w][f0][j + 4][k + 4];
    S2[w][f0][0][j][k] = 0.5f * (x00 + x11);
    S2[w][f0][1][j][k] = 0.5f * (x00 - x11);
    S2[w][f0][2][j][k] = 0.5f * (x01 + x10);
  }
  __syncthreads();
  if (tid < 144) {  // Phase 3c: + qubit2
    const int w = tid / 36, r = tid % 36;
    const int f0 = r / 12, f1 = (r >> 2) % 3, j = (r >> 1) & 1, k = r & 1;
    float x00 = S2[w][f0][f1][j][k],     x01 = S2[w][f0][f1][j][k + 2];
    float x10 = S2[w][f0][f1][j + 2][k], x11 = S2[w][f0][f1][j + 2][k + 2];
    S3[w][f0][f1][0][j][k] = 0.5f * (x00 + x11);
    S3[w][f0][f1][1][j][k] = 0.5f * (x00 - x11);
    S3[w][f0][f1][2][j][k] = 0.5f * (x01 + x10);
  }
  __syncthreads();
  if (tid < 108) {  // Phase 3d: + qubit3 -> float4 per (w,f0,f1,f2)
    const int w = tid / 27, r = tid % 27;
    const int f0 = r / 9, f1 = (r / 3) % 3, f2 = r % 3;
    float y00 = S3[w][f0][f1][f2][0][0], y01 = S3[w][f0][f1][f2][0][1];
    float y10 = S3[w][f0][f1][f2][1][0], y11 = S3[w][f0][f1][f2][1][1];
    float4 o;
    o.x = 0.5f * (y00 + y11);
    o.y = 0.5f * (y00 - y11);
    o.z = 0.5f * (y01 + y10);
    o.w = 0.f;
    ((float4*)g_coef)[tid] = o;
  }
}

// ---- main kernel: scalar-only state + LDS-staged coefficients -------------

#define TRIGM(xv, U, V) { \
  float e_  = __builtin_amdgcn_exp2f((xv) * 2.8853900817779268f); \
  float th_ = 1.0f - 2.0f * __builtin_amdgcn_rcpf(e_ + 1.0f); \
  U = __builtin_amdgcn_cosf(th_ * 0.25f); \
  V = __builtin_amdgcn_sinf(th_ * 0.25f); }

#define SAMPLE_TRIG(K) \
  TRIGM(X##K.x, u0_##K, v0_##K) TRIGM(X##K.y, u1_##K, v1_##K) \
  TRIGM(X##K.z, u2_##K, v2_##K) TRIGM(X##K.w, u3_##K, v3_##K)

#define ACC3(K) { \
  float t_ = fmaf(c.z, v3_##K, fmaf(c.y, u3_##K, c.x)); \
  if (e3 == 0) a3_##K = t_; \
  else a3_##K = fmaf(t_, (e3 == 1) ? u2_##K : v2_##K, a3_##K); }

#define ACC2(K) { \
  if (e2 == 0) a2_##K = a3_##K; \
  else a2_##K = fmaf(a3_##K, (e2 == 1) ? u1_##K : v1_##K, a2_##K); }

#define ACC1(K) { \
  if (e1 == 0) a1_##K = a2_##K; \
  else a1_##K = fmaf(a2_##K, (e1 == 1) ? u0_##K : v0_##K, a1_##K); }

#define CONTRACT(W) { \
  float a1_0, a1_1, a1_2, a1_3; \
  _Pragma("unroll") \
  for (int e1 = 0; e1 < 3; e1++) { \
    float a2_0, a2_1, a2_2, a2_3; \
    _Pragma("unroll") \
    for (int e2 = 0; e2 < 3; e2++) { \
      float a3_0, a3_1, a3_2, a3_3; \
      _Pragma("unroll") \
      for (int e3 = 0; e3 < 3; e3++) { \
        float4 c = Cs[(W) * 27 + (e1 * 3 + e2) * 3 + e3]; \
        ACC3(0) ACC3(1) ACC3(2) ACC3(3) \
      } \
      ACC2(0) ACC2(1) ACC2(2) ACC2(3) \
    } \
    ACC1(0) ACC1(1) ACC1(2) ACC1(3) \
    __builtin_amdgcn_sched_barrier(0); \
  } \
  o##W##_0 = a1_0; o##W##_1 = a1_1; o##W##_2 = a1_2; o##W##_3 = a1_3; }

__global__ __launch_bounds__(256) void qel_main(const float4* __restrict__ x4,
                                                float4* __restrict__ out4,
                                                int quarter) {
  __shared__ float4 Cs[108];
  const int tid = threadIdx.x;
  const int gid = blockIdx.x * 256 + tid;
  const bool act = gid < quarter;
  const int g = act ? gid : 0;

  // Issue sample loads + coefficient staging load first; both latencies
  // hide under the trig block (64 transcendental ops / thread).
  float4 X0 = x4[g];
  float4 X1 = x4[g + quarter];
  float4 X2 = x4[g + 2 * quarter];
  float4 X3 = x4[g + 3 * quarter];

  float4 cstage;
  if (tid < 108) cstage = ((const float4*)g_coef)[tid];

  float u0_0, v0_0, u1_0, v1_0, u2_0, v2_0, u3_0, v3_0;
  float u0_1, v0_1, u1_1, v1_1, u2_1, v2_1, u3_1, v3_1;
  float u0_2, v0_2, u1_2, v1_2, u2_2, v2_2, u3_2, v3_2;
  float u0_3, v0_3, u1_3, v1_3, u2_3, v2_3, u3_3, v3_3;
  SAMPLE_TRIG(0) SAMPLE_TRIG(1) SAMPLE_TRIG(2) SAMPLE_TRIG(3)

  if (tid < 108) Cs[tid] = cstage;
  __syncthreads();

  float o0_0, o0_1, o0_2, o0_3;
  float o1_0, o1_1, o1_2, o1_3;
  float o2_0, o2_1, o2_2, o2_3;
  float o3_0, o3_1, o3_2, o3_3;

  CONTRACT(0) CONTRACT(1) CONTRACT(2) CONTRACT(3)

  if (act) {
    out4[gid]               = make_float4(o0_0, o1_0, o2_0, o3_0);
    out4[gid + quarter]     = make_float4(o0_1, o1_1, o2_1, o3_1);
    out4[gid + 2 * quarter] = make_float4(o0_2, o1_2, o2_2, o3_2);
    out4[gid + 3 * quarter] = make_float4(o0_3, o1_3, o2_3, o3_3);
  }
}

// ---------------------------------------------------------------------------

extern "C" void kernel_launch(void* const* d_in, const int* in_sizes, int n_in,
                              void* d_out, int out_size, void* d_ws, size_t ws_size,
                              hipStream_t stream) {
  const float* x      = (const float*)d_in[0];   // [B,4] f32
  const float* params = (const float*)d_in[1];   // [2,4,3] f32
  float* out = (float*)d_out;                    // [B,4] f32

  int B = in_sizes[0] / 4;
  int quarter = B / 4;
  int blocks = (quarter + 255) / 256;

  qel_setup<<<1, 256, 0, stream>>>(params);
  // Dispatched TWICE on purpose (idempotent): total - 36.36us = one
  // qel_main duration. Decomposes the pinned 36us without rocprof top-5
  // visibility (harness fills at ~41us mask kernels below them).
  qel_main<<<blocks, 256, 0, stream>>>((const float4*)x, (float4*)out, quarter);
  qel_main<<<blocks, 256, 0, stream>>>((const float4*)x, (float4*)out, quarter);
}

// Round 9
// 42.270 us; speedup vs baseline: 1.4014x; 1.4014x over previous
//
#include <hip/hip_runtime.h>

// ---------------------------------------------------------------------------
// QuantumEntanglementLayer: 4 qubits, DIM=16, BATCH=2^20.
// out[b][w] = s^T A_w s,  A_w = Re(U^H Z_w U),  s = tensor prod of RY(|0>).
// Reduced to 4 multilinear polynomials with 81 coeffs each in (1,u_w,v_w),
// u_w = cos(tanh(x_w)*pi/2), v_w = sin(tanh(x_w)*pi/2).
//
// Measured decomposition (round 8, double-dispatch probe):
//   qel_main ~22.9us, qel_setup+overhead ~13.4us (one-block serial setup!).
// This revision: ONE fused kernel, with the round-2 VGPR balloon (240)
// fixed structurally: setup phase 1 is LDS-parallel (256 threads = col x row,
// state in LDS, ~10 live regs/thread, 16 gather/apply steps) instead of
// 16 lanes x 32 registers; CONTRACT keeps sched_barrier(0) per e1 to bound
// Cs-load hoisting to 9 float4. No occupancy attributes (measured poison).
// ---------------------------------------------------------------------------

__device__ __forceinline__ float hwsin(float rad) {
  return __builtin_amdgcn_sinf(rad * 0.15915494309189535f);  // rad -> rev
}
__device__ __forceinline__ float hwcos(float rad) {
  return __builtin_amdgcn_cosf(rad * 0.15915494309189535f);
}

// ---- main-phase macros ----------------------------------------------------

#define TRIGM(xv, U, V) { \
  float e_  = __builtin_amdgcn_exp2f((xv) * 2.8853900817779268f); \
  float th_ = 1.0f - 2.0f * __builtin_amdgcn_rcpf(e_ + 1.0f); \
  U = __builtin_amdgcn_cosf(th_ * 0.25f); \
  V = __builtin_amdgcn_sinf(th_ * 0.25f); }

#define SAMPLE_TRIG(K) \
  TRIGM(X##K.x, u0_##K, v0_##K) TRIGM(X##K.y, u1_##K, v1_##K) \
  TRIGM(X##K.z, u2_##K, v2_##K) TRIGM(X##K.w, u3_##K, v3_##K)

#define ACC3(K) { \
  float t_ = fmaf(c.z, v3_##K, fmaf(c.y, u3_##K, c.x)); \
  if (e3 == 0) a3_##K = t_; \
  else a3_##K = fmaf(t_, (e3 == 1) ? u2_##K : v2_##K, a3_##K); }

#define ACC2(K) { \
  if (e2 == 0) a2_##K = a3_##K; \
  else a2_##K = fmaf(a3_##K, (e2 == 1) ? u1_##K : v1_##K, a2_##K); }

#define ACC1(K) { \
  if (e1 == 0) a1_##K = a2_##K; \
  else a1_##K = fmaf(a2_##K, (e1 == 1) ? u0_##K : v0_##K, a1_##K); }

#define CONTRACT(W) { \
  float a1_0, a1_1, a1_2, a1_3; \
  _Pragma("unroll") \
  for (int e1 = 0; e1 < 3; e1++) { \
    float a2_0, a2_1, a2_2, a2_3; \
    _Pragma("unroll") \
    for (int e2 = 0; e2 < 3; e2++) { \
      float a3_0, a3_1, a3_2, a3_3; \
      _Pragma("unroll") \
      for (int e3 = 0; e3 < 3; e3++) { \
        float4 c = Cs[(W) * 27 + (e1 * 3 + e2) * 3 + e3]; \
        ACC3(0) ACC3(1) ACC3(2) ACC3(3) \
      } \
      ACC2(0) ACC2(1) ACC2(2) ACC2(3) \
    } \
    ACC1(0) ACC1(1) ACC1(2) ACC1(3) \
    __builtin_amdgcn_sched_barrier(0); \
  } \
  o##W##_0 = a1_0; o##W##_1 = a1_1; o##W##_2 = a1_2; o##W##_3 = a1_3; }

__global__ __launch_bounds__(256) void qel_fused(const float4* __restrict__ x4,
                                                 const float* __restrict__ params,
                                                 float4* __restrict__ out4,
                                                 int quarter) {
  __shared__ float2 U2[16][17];            // circuit state [col][row], +1 pad
  __shared__ float A[4][16][16];           // A_w
  __shared__ float S1[4][3][8][8];         // after contracting qubit0 (f0)
  __shared__ float S2[4][3][3][4][4];      // + qubit1 (f1)
  __shared__ float S3[4][3][3][3][2][2];   // + qubit2 (f2)
  __shared__ float4 Cs[108];               // final coefficients

  const int tid = threadIdx.x;
  const int gid = blockIdx.x * 256 + tid;
  const bool act = gid < quarter;
  const int g = act ? gid : 0;

  // Issue sample loads first: 16 regs live across the (lean) setup; HBM
  // latency fully hidden under the circuit + contraction phases.
  float4 X0 = x4[g];
  float4 X1 = x4[g + quarter];
  float4 X2 = x4[g + 2 * quarter];
  float4 X3 = x4[g + 3 * quarter];

  // ---- Setup phase 1 (LDS-parallel): U = circuit, one element/thread ----
  // Thread (c, r) owns column c (U e_c), row r. 2 layers x (3 CNOT +
  // 4 Rot + 1 CNOT) = 16 gather/apply steps, 2 barriers each.
  {
    const int c = tid >> 4, r = tid & 15;
    U2[c][r] = make_float2((r == c) ? 1.f : 0.f, 0.f);
    __syncthreads();

    #pragma unroll
    for (int layer = 0; layer < 2; layer++) {
      #pragma unroll
      for (int i = 0; i < 3; i++) {        // CNOT(i,i+1): cm=8>>i, tm=4>>i
        const int cm = 8 >> i, tm = 4 >> i;
        const int pr = (r & cm) ? (r ^ tm) : r;
        float2 v = U2[c][pr];
        __syncthreads();
        U2[c][r] = v;
        __syncthreads();
      }
      #pragma unroll
      for (int w = 0; w < 4; w++) {        // Rot(phi,theta,omega) on wire w
        float phi   = params[layer * 12 + w * 3 + 0];
        float theta = params[layer * 12 + w * 3 + 1];
        float omega = params[layer * 12 + w * 3 + 2];
        float ct = hwcos(theta * 0.5f), st = hwsin(theta * 0.5f);
        float ap = -0.5f * (phi + omega), am = 0.5f * (phi - omega);
        float g00r =  hwcos(ap) * ct, g00i =  hwsin(ap) * ct;
        float g01r = -hwcos(am) * st, g01i = -hwsin(am) * st;
        float g10r =  hwcos(am) * st, g10i = -hwsin(am) * st;
        float g11r =  g00r,           g11i = -g00i;
        const int tm = 8 >> w;
        const int r0 = r & ~tm, r1 = r | tm;
        const bool hi = (r & tm) != 0;
        float gar = hi ? g10r : g00r, gai = hi ? g10i : g00i;
        float gbr = hi ? g11r : g01r, gbi = hi ? g11i : g01i;
        float2 o0 = U2[c][r0], o1 = U2[c][r1];
        __syncthreads();
        float nr = gar * o0.x - gai * o0.y + gbr * o1.x - gbi * o1.y;
        float ni = gar * o0.y + gai * o0.x + gbr * o1.y + gbi * o1.x;
        U2[c][r] = make_float2(nr, ni);
        __syncthreads();
      }
      {                                    // CNOT(0,3): cm=8, tm=1
        const int pr = (r & 8) ? (r ^ 1) : r;
        float2 v = U2[c][pr];
        __syncthreads();
        U2[c][r] = v;
        __syncthreads();
      }
    }
  }

  // ---- Setup phase 2: A_w[j][k] = sum_i z_w[i] Re(conj(U_ij) U_ik) -------
  {
    const int j = tid >> 4, k = tid & 15;
    float s0 = 0.f, s1 = 0.f, s2 = 0.f, s3 = 0.f;
    #pragma unroll
    for (int i = 0; i < 16; i++) {
      float2 uj = U2[j][i], uk = U2[k][i];
      float p = uj.x * uk.x + uj.y * uk.y;
      s0 += (i & 8) ? -p : p;
      s1 += (i & 4) ? -p : p;
      s2 += (i & 2) ? -p : p;
      s3 += (i & 1) ? -p : p;
    }
    A[0][j][k] = s0; A[1][j][k] = s1; A[2][j][k] = s2; A[3][j][k] = s3;
  }
  __syncthreads();

  // Basis per 2x2 block: f=0: .5(x00+x11)  f=1: .5(x00-x11)  f=2: .5(x01+x10)
  {  // Phase 3a: contract qubit0 (bit3)
    const int w = tid >> 6, j = (tid >> 3) & 7, k = tid & 7;
    float x00 = A[w][j][k],     x01 = A[w][j][k + 8];
    float x10 = A[w][j + 8][k], x11 = A[w][j + 8][k + 8];
    S1[w][0][j][k] = 0.5f * (x00 + x11);
    S1[w][1][j][k] = 0.5f * (x00 - x11);
    S1[w][2][j][k] = 0.5f * (x01 + x10);
  }
  __syncthreads();
  if (tid < 192) {  // Phase 3b: + qubit1
    const int w = tid / 48, r = tid % 48;
    const int f0 = r >> 4, j = (r >> 2) & 3, k = r & 3;
    float x00 = S1[w][f0][j][k],     x01 = S1[w][f0][j][k + 4];
    float x10 = S1[w][f0][j + 4][k], x11 = S1[w][f0][j + 4][k + 4];
    S2[w][f0][0][j][k] = 0.5f * (x00 + x11);
    S2[w][f0][1][j][k] = 0.5f * (x00 - x11);
    S2[w][f0][2][j][k] = 0.5f * (x01 + x10);
  }
  __syncthreads();
  if (tid < 144) {  // Phase 3c: + qubit2
    const int w = tid / 36, r = tid % 36;
    const int f0 = r / 12, f1 = (r >> 2) % 3, j = (r >> 1) & 1, k = r & 1;
    float x00 = S2[w][f0][f1][j][k],     x01 = S2[w][f0][f1][j][k + 2];
    float x10 = S2[w][f0][f1][j + 2][k], x11 = S2[w][f0][f1][j + 2][k + 2];
    S3[w][f0][f1][0][j][k] = 0.5f * (x00 + x11);
    S3[w][f0][f1][1][j][k] = 0.5f * (x00 - x11);
    S3[w][f0][f1][2][j][k] = 0.5f * (x01 + x10);
  }
  __syncthreads();
  if (tid < 108) {  // Phase 3d: + qubit3 -> float4 per (w,f0,f1,f2)
    const int w = tid / 27, r = tid % 27;
    const int f0 = r / 9, f1 = (r / 3) % 3, f2 = r % 3;
    float y00 = S3[w][f0][f1][f2][0][0], y01 = S3[w][f0][f1][f2][0][1];
    float y10 = S3[w][f0][f1][f2][1][0], y11 = S3[w][f0][f1][f2][1][1];
    float4 o;
    o.x = 0.5f * (y00 + y11);
    o.y = 0.5f * (y00 - y11);
    o.z = 0.5f * (y01 + y10);
    o.w = 0.f;
    Cs[tid] = o;
  }

  // ---- Per-sample trig (all threads, before the final barrier) -----------
  float u0_0, v0_0, u1_0, v1_0, u2_0, v2_0, u3_0, v3_0;
  float u0_1, v0_1, u1_1, v1_1, u2_1, v2_1, u3_1, v3_1;
  float u0_2, v0_2, u1_2, v1_2, u2_2, v2_2, u3_2, v3_2;
  float u0_3, v0_3, u1_3, v1_3, u2_3, v2_3, u3_3, v3_3;
  SAMPLE_TRIG(0) SAMPLE_TRIG(1) SAMPLE_TRIG(2) SAMPLE_TRIG(3)

  __syncthreads();

  // ---- Polynomial contraction (all state in named scalars) ---------------
  float o0_0, o0_1, o0_2, o0_3;
  float o1_0, o1_1, o1_2, o1_3;
  float o2_0, o2_1, o2_2, o2_3;
  float o3_0, o3_1, o3_2, o3_3;

  CONTRACT(0) CONTRACT(1) CONTRACT(2) CONTRACT(3)

  if (act) {
    out4[gid]               = make_float4(o0_0, o1_0, o2_0, o3_0);
    out4[gid + quarter]     = make_float4(o0_1, o1_1, o2_1, o3_1);
    out4[gid + 2 * quarter] = make_float4(o0_2, o1_2, o2_2, o3_2);
    out4[gid + 3 * quarter] = make_float4(o0_3, o1_3, o2_3, o3_3);
  }
}

// ---------------------------------------------------------------------------

extern "C" void kernel_launch(void* const* d_in, const int* in_sizes, int n_in,
                              void* d_out, int out_size, void* d_ws, size_t ws_size,
                              hipStream_t stream) {
  const float* x      = (const float*)d_in[0];   // [B,4] f32
  const float* params = (const float*)d_in[1];   // [2,4,3] f32
  float* out = (float*)d_out;                    // [B,4] f32

  int B = in_sizes[0] / 4;
  int quarter = B / 4;
  int blocks = (quarter + 255) / 256;

  qel_fused<<<blocks, 256, 0, stream>>>((const float4*)x, params,
                                        (float4*)out, quarter);
}

// Round 10
// 34.805 us; speedup vs baseline: 1.7020x; 1.2145x over previous
//
#include <hip/hip_runtime.h>

// ---------------------------------------------------------------------------
// QuantumEntanglementLayer: 4 qubits, DIM=16, BATCH=2^20.
// out[b][w] = s^T A_w s,  A_w = Re(U^H Z_w U),  s = tensor prod of RY(|0>).
// Reduced to 4 multilinear polynomials with 81 coeffs each in (1,u_w,v_w),
// u_w = cos(tanh(x_w)*pi/2), v_w = sin(tanh(x_w)*pi/2).
//
// Measured decomposition (round-8 double-dispatch probe, 36.3us total):
//   qel_setup + overhead ~13.4us   qel_main ~22.9us
// Round 9 measured the LDS-parallel circuit saves ~8us of setup serial time
// (fused 50.7 -> 42.3) but fused stays 256-VGPR/2-wave latency-bound.
// This revision: keep the two-kernel split (main untouched, 22.9us) and
// make qel_setup LDS-parallel: 256 threads = (col,row), one complex element
// per thread, 16 gather/apply steps. Kills the single-wave serial tail.
// ---------------------------------------------------------------------------

// Coefficients: [4 wires][27 (f0,f1,f2)][4 (f3 in .x/.y/.z, .w = pad)]
__device__ float g_coef[4 * 27 * 4];

__device__ __forceinline__ float hwsin(float rad) {
  return __builtin_amdgcn_sinf(rad * 0.15915494309189535f);  // rad -> rev
}
__device__ __forceinline__ float hwcos(float rad) {
  return __builtin_amdgcn_cosf(rad * 0.15915494309189535f);
}

__global__ __launch_bounds__(256) void qel_setup(const float* __restrict__ params) {
  __shared__ float2 U2[16][17];            // circuit state [col][row], +1 pad
  __shared__ float A[4][16][16];           // A_w
  __shared__ float S1[4][3][8][8];         // after contracting qubit0 (f0)
  __shared__ float S2[4][3][3][4][4];      // + qubit1 (f1)
  __shared__ float S3[4][3][3][3][2][2];   // + qubit2 (f2)
  const int tid = threadIdx.x;

  // ---- Phase 1 (LDS-parallel): U = circuit, one element per thread -------
  // Thread (c, r) owns column c (U e_c), row r. 2 layers x (3 CNOT +
  // 4 Rot + 1 CNOT) = 16 gather/apply steps, 2 barriers each.
  {
    const int c = tid >> 4, r = tid & 15;
    U2[c][r] = make_float2((r == c) ? 1.f : 0.f, 0.f);
    __syncthreads();

    #pragma unroll
    for (int layer = 0; layer < 2; layer++) {
      #pragma unroll
      for (int i = 0; i < 3; i++) {        // CNOT(i,i+1): cm=8>>i, tm=4>>i
        const int cm = 8 >> i, tm = 4 >> i;
        const int pr = (r & cm) ? (r ^ tm) : r;
        float2 v = U2[c][pr];
        __syncthreads();
        U2[c][r] = v;
        __syncthreads();
      }
      #pragma unroll
      for (int w = 0; w < 4; w++) {        // Rot(phi,theta,omega) on wire w
        float phi   = params[layer * 12 + w * 3 + 0];
        float theta = params[layer * 12 + w * 3 + 1];
        float omega = params[layer * 12 + w * 3 + 2];
        float ct = hwcos(theta * 0.5f), st = hwsin(theta * 0.5f);
        float ap = -0.5f * (phi + omega), am = 0.5f * (phi - omega);
        float g00r =  hwcos(ap) * ct, g00i =  hwsin(ap) * ct;
        float g01r = -hwcos(am) * st, g01i = -hwsin(am) * st;
        float g10r =  hwcos(am) * st, g10i = -hwsin(am) * st;
        float g11r =  g00r,           g11i = -g00i;
        const int tm = 8 >> w;
        const int r0 = r & ~tm, r1 = r | tm;
        const bool hi = (r & tm) != 0;
        float gar = hi ? g10r : g00r, gai = hi ? g10i : g00i;
        float gbr = hi ? g11r : g01r, gbi = hi ? g11i : g01i;
        float2 o0 = U2[c][r0], o1 = U2[c][r1];
        __syncthreads();
        float nr = gar * o0.x - gai * o0.y + gbr * o1.x - gbi * o1.y;
        float ni = gar * o0.y + gai * o0.x + gbr * o1.y + gbi * o1.x;
        U2[c][r] = make_float2(nr, ni);
        __syncthreads();
      }
      {                                    // CNOT(0,3): cm=8, tm=1
        const int pr = (r & 8) ? (r ^ 1) : r;
        float2 v = U2[c][pr];
        __syncthreads();
        U2[c][r] = v;
        __syncthreads();
      }
    }
  }

  // ---- Phase 2: A_w[j][k] = sum_i z_w[i] Re(conj(U_ij) U_ik) -------------
  {
    const int j = tid >> 4, k = tid & 15;
    float s0 = 0.f, s1 = 0.f, s2 = 0.f, s3 = 0.f;
    #pragma unroll
    for (int i = 0; i < 16; i++) {
      float2 uj = U2[j][i], uk = U2[k][i];
      float p = uj.x * uk.x + uj.y * uk.y;
      s0 += (i & 8) ? -p : p;
      s1 += (i & 4) ? -p : p;
      s2 += (i & 2) ? -p : p;
      s3 += (i & 1) ? -p : p;
    }
    A[0][j][k] = s0; A[1][j][k] = s1; A[2][j][k] = s2; A[3][j][k] = s3;
  }
  __syncthreads();

  // Basis per 2x2 block: f=0: .5(x00+x11)  f=1: .5(x00-x11)  f=2: .5(x01+x10)
  {  // Phase 3a: contract qubit0 (bit3)
    const int w = tid >> 6, j = (tid >> 3) & 7, k = tid & 7;
    float x00 = A[w][j][k],     x01 = A[w][j][k + 8];
    float x10 = A[w][j + 8][k], x11 = A[w][j + 8][k + 8];
    S1[w][0][j][k] = 0.5f * (x00 + x11);
    S1[w][1][j][k] = 0.5f * (x00 - x11);
    S1[w][2][j][k] = 0.5f * (x01 + x10);
  }
  __syncthreads();
  if (tid < 192) {  // Phase 3b: + qubit1
    const int w = tid / 48, r = tid % 48;
    const int f0 = r >> 4, j = (r >> 2) & 3, k = r & 3;
    float x00 = S1[w][f0][j][k],     x01 = S1[w][f0][j][k + 4];
    float x10 = S1[w][f0][j + 4][k], x11 = S1[w][f0][j + 4][k + 4];
    S2[w][f0][0][j][k] = 0.5f * (x00 + x11);
    S2[w][f0][1][j][k] = 0.5f * (x00 - x11);
    S2[w][f0][2][j][k] = 0.5f * (x01 + x10);
  }
  __syncthreads();
  if (tid < 144) {  // Phase 3c: + qubit2
    const int w = tid / 36, r = tid % 36;
    const int f0 = r / 12, f1 = (r >> 2) % 3, j = (r >> 1) & 1, k = r & 1;
    float x00 = S2[w][f0][f1][j][k],     x01 = S2[w][f0][f1][j][k + 2];
    float x10 = S2[w][f0][f1][j + 2][k], x11 = S2[w][f0][f1][j + 2][k + 2];
    S3[w][f0][f1][0][j][k] = 0.5f * (x00 + x11);
    S3[w][f0][f1][1][j][k] = 0.5f * (x00 - x11);
    S3[w][f0][f1][2][j][k] = 0.5f * (x01 + x10);
  }
  __syncthreads();
  if (tid < 108) {  // Phase 3d: + qubit3 -> float4 per (w,f0,f1,f2)
    const int w = tid / 27, r = tid % 27;
    const int f0 = r / 9, f1 = (r / 3) % 3, f2 = r % 3;
    float y00 = S3[w][f0][f1][f2][0][0], y01 = S3[w][f0][f1][f2][0][1];
    float y10 = S3[w][f0][f1][f2][1][0], y11 = S3[w][f0][f1][f2][1][1];
    float4 o;
    o.x = 0.5f * (y00 + y11);
    o.y = 0.5f * (y00 - y11);
    o.z = 0.5f * (y01 + y10);
    o.w = 0.f;
    ((float4*)g_coef)[tid] = o;
  }
}

// ---- main kernel: round-6 byte-for-byte (measured 22.9us) -----------------

#define TRIGM(xv, U, V) { \
  float e_  = __builtin_amdgcn_exp2f((xv) * 2.8853900817779268f); \
  float th_ = 1.0f - 2.0f * __builtin_amdgcn_rcpf(e_ + 1.0f); \
  U = __builtin_amdgcn_cosf(th_ * 0.25f); \
  V = __builtin_amdgcn_sinf(th_ * 0.25f); }

#define SAMPLE_TRIG(K) \
  TRIGM(X##K.x, u0_##K, v0_##K) TRIGM(X##K.y, u1_##K, v1_##K) \
  TRIGM(X##K.z, u2_##K, v2_##K) TRIGM(X##K.w, u3_##K, v3_##K)

#define ACC3(K) { \
  float t_ = fmaf(c.z, v3_##K, fmaf(c.y, u3_##K, c.x)); \
  if (e3 == 0) a3_##K = t_; \
  else a3_##K = fmaf(t_, (e3 == 1) ? u2_##K : v2_##K, a3_##K); }

#define ACC2(K) { \
  if (e2 == 0) a2_##K = a3_##K; \
  else a2_##K = fmaf(a3_##K, (e2 == 1) ? u1_##K : v1_##K, a2_##K); }

#define ACC1(K) { \
  if (e1 == 0) a1_##K = a2_##K; \
  else a1_##K = fmaf(a2_##K, (e1 == 1) ? u0_##K : v0_##K, a1_##K); }

#define CONTRACT(W) { \
  float a1_0, a1_1, a1_2, a1_3; \
  _Pragma("unroll") \
  for (int e1 = 0; e1 < 3; e1++) { \
    float a2_0, a2_1, a2_2, a2_3; \
    _Pragma("unroll") \
    for (int e2 = 0; e2 < 3; e2++) { \
      float a3_0, a3_1, a3_2, a3_3; \
      _Pragma("unroll") \
      for (int e3 = 0; e3 < 3; e3++) { \
        float4 c = Cs[(W) * 27 + (e1 * 3 + e2) * 3 + e3]; \
        ACC3(0) ACC3(1) ACC3(2) ACC3(3) \
      } \
      ACC2(0) ACC2(1) ACC2(2) ACC2(3) \
    } \
    ACC1(0) ACC1(1) ACC1(2) ACC1(3) \
    __builtin_amdgcn_sched_barrier(0); \
  } \
  o##W##_0 = a1_0; o##W##_1 = a1_1; o##W##_2 = a1_2; o##W##_3 = a1_3; }

__global__ __launch_bounds__(256) void qel_main(const float4* __restrict__ x4,
                                                float4* __restrict__ out4,
                                                int quarter) {
  __shared__ float4 Cs[108];
  const int tid = threadIdx.x;
  const int gid = blockIdx.x * 256 + tid;
  const bool act = gid < quarter;
  const int g = act ? gid : 0;

  // Issue sample loads + coefficient staging load first; both latencies
  // hide under the trig block (64 transcendental ops / thread).
  float4 X0 = x4[g];
  float4 X1 = x4[g + quarter];
  float4 X2 = x4[g + 2 * quarter];
  float4 X3 = x4[g + 3 * quarter];

  float4 cstage;
  if (tid < 108) cstage = ((const float4*)g_coef)[tid];

  float u0_0, v0_0, u1_0, v1_0, u2_0, v2_0, u3_0, v3_0;
  float u0_1, v0_1, u1_1, v1_1, u2_1, v2_1, u3_1, v3_1;
  float u0_2, v0_2, u1_2, v1_2, u2_2, v2_2, u3_2, v3_2;
  float u0_3, v0_3, u1_3, v1_3, u2_3, v2_3, u3_3, v3_3;
  SAMPLE_TRIG(0) SAMPLE_TRIG(1) SAMPLE_TRIG(2) SAMPLE_TRIG(3)

  if (tid < 108) Cs[tid] = cstage;
  __syncthreads();

  float o0_0, o0_1, o0_2, o0_3;
  float o1_0, o1_1, o1_2, o1_3;
  float o2_0, o2_1, o2_2, o2_3;
  float o3_0, o3_1, o3_2, o3_3;

  CONTRACT(0) CONTRACT(1) CONTRACT(2) CONTRACT(3)

  if (act) {
    out4[gid]               = make_float4(o0_0, o1_0, o2_0, o3_0);
    out4[gid + quarter]     = make_float4(o0_1, o1_1, o2_1, o3_1);
    out4[gid + 2 * quarter] = make_float4(o0_2, o1_2, o2_2, o3_2);
    out4[gid + 3 * quarter] = make_float4(o0_3, o1_3, o2_3, o3_3);
  }
}

// ---------------------------------------------------------------------------

extern "C" void kernel_launch(void* const* d_in, const int* in_sizes, int n_in,
                              void* d_out, int out_size, void* d_ws, size_t ws_size,
                              hipStream_t stream) {
  const float* x      = (const float*)d_in[0];   // [B,4] f32
  const float* params = (const float*)d_in[1];   // [2,4,3] f32
  float* out = (float*)d_out;                    // [B,4] f32

  int B = in_sizes[0] / 4;
  int quarter = B / 4;
  int blocks = (quarter + 255) / 256;

  qel_setup<<<1, 256, 0, stream>>>(params);
  qel_main<<<blocks, 256, 0, stream>>>((const float4*)x, (float4*)out, quarter);
}